// Round 14
// baseline (52.652 us; speedup 1.0000x reference)
//
#include <hip/hip_runtime.h>

// Problem constants (fixed by reference): S=256, B=64, D=1024, T=64
#define SLEN 256
#define NB   64
#define ND   1024
#define NT   64
#define APAD 1032   // bf16 elems per LDS A-row (1024 + 8; keeps 16B row alignment)
// BOS=0, EOS=1, PAD=2

typedef float f32x4  __attribute__((ext_vector_type(4)));
typedef short bf16x8 __attribute__((ext_vector_type(8)));
typedef unsigned int u32;
typedef u32 u32x2 __attribute__((ext_vector_type(2)));
typedef u32 u32x4 __attribute__((ext_vector_type(4)));

__device__ __forceinline__ u32 cvt_pk_bf16(float lo, float hi) {
  u32 r;
  asm("v_cvt_pk_bf16_f32 %0, %1, %2" : "=v"(r) : "v"(lo), "v"(hi));
  return r;
}

__device__ __forceinline__ unsigned short f2bf(float f) {   // RNE
  u32 u = __float_as_uint(f);
  return (unsigned short)((u + 0x7FFFu + ((u >> 16) & 1u)) >> 16);
}

// ---------------------------------------------------------------------------
// Kernel 0: blocks 0..255: W -> bf16 frag-stream (B-frag of 16x16x32).
//           block 256:     bf16 hi/lo E'^T A-frag table (16 KB) + out[0]=0.
// E-frag elem e, lane l=(q,c), tile (mt,kf):
//   exp(trans[(32kf+8q+e)*64 + 16mt+c]) * 2^-6, RNE-split into bf16 hi + lo.
// (R3/R4-proven: absmax 0.0 at 16-step chunks)
// ---------------------------------------------------------------------------
__global__ __launch_bounds__(256) void prep(const float* __restrict__ W,
                                            const float* __restrict__ trans,
                                            unsigned short* __restrict__ Wb3,
                                            u32* __restrict__ Ebuf,
                                            float* __restrict__ out) {
  if (blockIdx.x < 256) {
    int o  = blockIdx.x * 256 + threadIdx.x;          // 0..65535
    int e  = o & 7;
    int l  = (o >> 3) & 63;
    int f  = (o >> 9) & 3;
    int k0 = o >> 11;
    int t  = f * 16 + (l & 15);
    int k  = k0 * 32 + ((l >> 4) << 3) + e;
    Wb3[o] = f2bf(W[t * ND + k]);
    return;
  }
  const int tid = threadIdx.x;
  if (tid == 0) out[0] = 0.f;
  const int l = tid & 63, wd = tid >> 6;              // wd = word 0..3
  const int q = l >> 4, c = l & 15;
#pragma unroll
  for (int mt = 0; mt < 4; ++mt)
#pragma unroll
    for (int kf = 0; kf < 2; ++kf) {
      float v0 = __expf(trans[(32 * kf + 8 * q + 2 * wd)     * NT + 16 * mt + c]) * 0.015625f;
      float v1 = __expf(trans[(32 * kf + 8 * q + 2 * wd + 1) * NT + 16 * mt + c]) * 0.015625f;
      u32 u0 = __float_as_uint(v0), u1 = __float_as_uint(v1);
      float h0 = __uint_as_float((u0 + 0x7FFFu + ((u0 >> 16) & 1u)) & 0xFFFF0000u);
      float h1 = __uint_as_float((u1 + 0x7FFFu + ((u1 >> 16) & 1u)) & 0xFFFF0000u);
      Ebuf[((mt * 2 + kf) * 2 + 0) * 256 + l * 4 + wd] = cvt_pk_bf16(h0, h1);
      Ebuf[((mt * 2 + kf) * 2 + 1) * 256 + l * 4 + wd] = cvt_pk_bf16(v0 - h0, v1 - h1);
    }
}

// ---------------------------------------------------------------------------
// Kernel 1: xbuf[r][t] = bf16( exp( features[r]·W[t] + b[t] ) ), r = s*B+b.
// (R11: coalesced-staged A; proven)
// ---------------------------------------------------------------------------
__global__ __launch_bounds__(256) void emit_gemm(const float* __restrict__ F,
                                                 const unsigned short* __restrict__ Wb3,
                                                 const float* __restrict__ bias,
                                                 unsigned short* __restrict__ xbuf) {
  __shared__ union ShU {
    unsigned short a[16 * APAD];   // 33 KB staged A (bf16)
    float comb[4][64][17];         // 17.4 KB combine (after barrier)
  } sh;
  const int tid = threadIdx.x;
  const int w   = tid >> 6;               // wave 0..3 = K-quarter / tag block
  const int l   = tid & 63;
  const int q   = l >> 4;                 // out row group 0..3
  const int c   = l & 15;                 // A row / out tag col

  const int blk = blockIdx.x;             // 16-row strip id
  const float* fb = F + (size_t)blk * 16 * ND;

#pragma unroll 8
  for (int i = 0; i < 16; ++i) {
    f32x4 v = *(const f32x4*)(fb + i * ND + tid * 4);
    u32x2 p;
    p.x = cvt_pk_bf16(v.x, v.y);
    p.y = cvt_pk_bf16(v.z, v.w);
    *(u32x2*)(sh.a + i * APAD + tid * 4) = p;
  }
  __syncthreads();

  f32x4 acc0 = {0.f, 0.f, 0.f, 0.f};
  f32x4 acc1 = acc0, acc2 = acc0, acc3 = acc0;
  const bf16x8* bptr = reinterpret_cast<const bf16x8*>(Wb3) + l;
  const unsigned short* arow = sh.a + c * APAD + q * 8;

#pragma unroll
  for (int g = 0; g < 8; ++g) {
    int ks = w * 8 + g;
    bf16x8 af = *(const bf16x8*)(arow + ks * 32);
    bf16x8 b0 = bptr[(ks * 4 + 0) * 64];
    bf16x8 b1 = bptr[(ks * 4 + 1) * 64];
    bf16x8 b2 = bptr[(ks * 4 + 2) * 64];
    bf16x8 b3 = bptr[(ks * 4 + 3) * 64];
    acc0 = __builtin_amdgcn_mfma_f32_16x16x32_bf16(af, b0, acc0, 0, 0, 0);
    acc1 = __builtin_amdgcn_mfma_f32_16x16x32_bf16(af, b1, acc1, 0, 0, 0);
    acc2 = __builtin_amdgcn_mfma_f32_16x16x32_bf16(af, b2, acc2, 0, 0, 0);
    acc3 = __builtin_amdgcn_mfma_f32_16x16x32_bf16(af, b3, acc3, 0, 0, 0);
  }

  __syncthreads();
#pragma unroll
  for (int r = 0; r < 4; ++r) {
    sh.comb[w][l][r]      = acc0[r];
    sh.comb[w][l][4 + r]  = acc1[r];
    sh.comb[w][l][8 + r]  = acc2[r];
    sh.comb[w][l][12 + r] = acc3[r];
  }
  __syncthreads();

  {
    float s[4];
#pragma unroll
    for (int r = 0; r < 4; ++r)
      s[r] = sh.comb[0][l][4 * w + r] + sh.comb[1][l][4 * w + r]
           + sh.comb[2][l][4 * w + r] + sh.comb[3][l][4 * w + r];
    const float bv = bias[16 * w + c];
    unsigned short* op = xbuf + (size_t)(blk * 16 + q * 4) * NT + 16 * w + c;
#pragma unroll
    for (int r = 0; r < 4; ++r)
      op[r * NT] = f2bf(__expf(s[r] + bv));
  }
}

// ---------------------------------------------------------------------------
// Kernel 2: per-(batch,chunk) product matrix, 16 steps, bf16 hi/lo MFMA
// (16/step, no renorm needed: bf16 has f32 exponent range). 1024 blocks at
// 4 blocks/CU. x staged to LDS; gold partial to Gpart. (numerics = R3/R4)
// ---------------------------------------------------------------------------
__global__ __launch_bounds__(256, 4) void chunk_prod(
    const unsigned short* __restrict__ xbuf, const float* __restrict__ trans,
    const u32* __restrict__ Ebuf, const int* __restrict__ tags,
    const int* __restrict__ seq_lens, unsigned short* __restrict__ Gout,
    float* __restrict__ Gpart) {
  __shared__ float trs[64 * 68];
  __shared__ unsigned short xlds[16 * 64];
  const int b   = blockIdx.x >> 4;
  const int k   = blockIdx.x & 15;
  const int tid = threadIdx.x;
  const int wid = tid >> 6;           // wave id = 16-column tile
  const int l   = tid & 63;
  const int q   = l >> 4, c = l & 15;

  const int L = seq_lens[b];          // in [2,256]

  // ---- stage x-chunk to LDS: rows t = 16k .. 16k+15 of batch b (2 KB) ----
  if (tid < 128) {
    int tp  = tid >> 3;               // 0..15
    int cg  = (tid & 7) * 8;          // 8 bf16 per thread
    const u32x4* s4 = (const u32x4*)(xbuf + ((size_t)((16 * k + tp) * NB + b)) * NT + cg);
    *(u32x4*)(xlds + tp * 64 + cg) = *s4;
  }

  // ---- gold slice: s in [16k, 16k+16) ∩ [0,L), wave 0 lanes 0..15 ----
  if (wid == 0) {
    float gp = 0.f;
    int s = 16 * k + (l & 15);
    if (l < 16 && s < L) {
      int tg = tags[s * NB + b];
      int nx = (s + 1 < SLEN) ? tags[(s + 1) * NB + b] : 2;
      float xv = __uint_as_float((u32)xbuf[(size_t)(s * NB + b) * NT + tg] << 16);
      gp = __logf(xv) + trans[tg * NT + nx];
    }
    gp += __shfl_xor(gp, 1, 64);
    gp += __shfl_xor(gp, 2, 64);
    gp += __shfl_xor(gp, 4, 64);
    gp += __shfl_xor(gp, 8, 64);
    if (l == 0) Gpart[b * 16 + k] = gp;
  }

  // ---- resident bf16 hi/lo E'^T A-frags (64 VGPRs) ----
  union uf { u32x4 u; bf16x8 v; };
  uf eh[4][2], el[4][2];
#pragma unroll
  for (int mt = 0; mt < 4; ++mt)
#pragma unroll
    for (int kf = 0; kf < 2; ++kf) {
      eh[mt][kf].u = *(const u32x4*)(Ebuf + ((mt * 2 + kf) * 2 + 0) * 256 + l * 4);
      el[mt][kf].u = *(const u32x4*)(Ebuf + ((mt * 2 + kf) * 2 + 1) * 256 + l * 4);
    }

  // ---- G = I (this wave's 16-column tile): G[16mt+4q+r][16wid+c] ----
  f32x4 g0 = {0,0,0,0}, g1 = g0, g2 = g0, g3 = g0;
  {
    int r = c - 4 * q;
    if (r >= 0 && r < 4) {
      float one = 1.0f;
      if (wid == 0) g0[r & 3] = one;
      else if (wid == 1) g1[r & 3] = one;
      else if (wid == 2) g2[r & 3] = one;
      else g3[r & 3] = one;
    }
  }

  int tbeg = 16 * k; if (tbeg < 1) tbeg = 1;
  int tend = 16 * k + 16; if (tend > L) tend = L;

  __syncthreads();                    // xlds ready

#define SWAPQ(A, B) do {                                                  \
    asm("v_permlane32_swap_b32 %0, %1" : "+v"(A), "+v"(B));               \
    asm("v_permlane16_swap_b32 %0, %1" : "+v"(A), "+v"(B));               \
  } while (0)

#define LOADX(X, TP) do {                                                 \
    X[0] = *(const u32x2*)(xlds + (TP) * 64 + 4 * q);                     \
    X[1] = *(const u32x2*)(xlds + (TP) * 64 + 16 + 4 * q);                \
    X[2] = *(const u32x2*)(xlds + (TP) * 64 + 32 + 4 * q);                \
    X[3] = *(const u32x2*)(xlds + (TP) * 64 + 48 + 4 * q);                \
  } while (0)

#define MULPK(P0, P1, G, XW) do {                                         \
    f32x4 xv;                                                             \
    xv.x = __uint_as_float(XW.x << 16);                                   \
    xv.y = __uint_as_float(XW.x & 0xFFFF0000u);                           \
    xv.z = __uint_as_float(XW.y << 16);                                   \
    xv.w = __uint_as_float(XW.y & 0xFFFF0000u);                           \
    f32x4 ww = G * xv;                                                    \
    P0 = cvt_pk_bf16(ww.x, ww.y);                                         \
    P1 = cvt_pk_bf16(ww.z, ww.w);                                         \
  } while (0)

#define STEPF(X) do {                                                     \
    u32 p00, p01, p10, p11, p20, p21, p30, p31;                           \
    MULPK(p00, p01, g0, X[0]);                                            \
    MULPK(p10, p11, g1, X[1]);                                            \
    MULPK(p20, p21, g2, X[2]);                                            \
    MULPK(p30, p31, g3, X[3]);                                            \
    SWAPQ(p00, p10); SWAPQ(p01, p11); SWAPQ(p20, p30); SWAPQ(p21, p31);   \
    uf B0, B1;                                                            \
    B0.u[0] = p00; B0.u[1] = p01; B0.u[2] = p10; B0.u[3] = p11;           \
    B1.u[0] = p20; B1.u[1] = p21; B1.u[2] = p30; B1.u[3] = p31;           \
    const f32x4 zz = {0.f, 0.f, 0.f, 0.f};                                \
    f32x4 dh, dl;                                                         \
    dh = __builtin_amdgcn_mfma_f32_16x16x32_bf16(eh[0][0].v, B0.v, zz, 0, 0, 0); \
    dh = __builtin_amdgcn_mfma_f32_16x16x32_bf16(eh[0][1].v, B1.v, dh, 0, 0, 0); \
    dl = __builtin_amdgcn_mfma_f32_16x16x32_bf16(el[0][0].v, B0.v, zz, 0, 0, 0); \
    dl = __builtin_amdgcn_mfma_f32_16x16x32_bf16(el[0][1].v, B1.v, dl, 0, 0, 0); \
    g0 = dh + dl;                                                         \
    dh = __builtin_amdgcn_mfma_f32_16x16x32_bf16(eh[1][0].v, B0.v, zz, 0, 0, 0); \
    dh = __builtin_amdgcn_mfma_f32_16x16x32_bf16(eh[1][1].v, B1.v, dh, 0, 0, 0); \
    dl = __builtin_amdgcn_mfma_f32_16x16x32_bf16(el[1][0].v, B0.v, zz, 0, 0, 0); \
    dl = __builtin_amdgcn_mfma_f32_16x16x32_bf16(el[1][1].v, B1.v, dl, 0, 0, 0); \
    g1 = dh + dl;                                                         \
    dh = __builtin_amdgcn_mfma_f32_16x16x32_bf16(eh[2][0].v, B0.v, zz, 0, 0, 0); \
    dh = __builtin_amdgcn_mfma_f32_16x16x32_bf16(eh[2][1].v, B1.v, dh, 0, 0, 0); \
    dl = __builtin_amdgcn_mfma_f32_16x16x32_bf16(el[2][0].v, B0.v, zz, 0, 0, 0); \
    dl = __builtin_amdgcn_mfma_f32_16x16x32_bf16(el[2][1].v, B1.v, dl, 0, 0, 0); \
    g2 = dh + dl;                                                         \
    dh = __builtin_amdgcn_mfma_f32_16x16x32_bf16(eh[3][0].v, B0.v, zz, 0, 0, 0); \
    dh = __builtin_amdgcn_mfma_f32_16x16x32_bf16(eh[3][1].v, B1.v, dh, 0, 0, 0); \
    dl = __builtin_amdgcn_mfma_f32_16x16x32_bf16(el[3][0].v, B0.v, zz, 0, 0, 0); \
    dl = __builtin_amdgcn_mfma_f32_16x16x32_bf16(el[3][1].v, B1.v, dl, 0, 0, 0); \
    g3 = dh + dl;                                                         \
  } while (0)

  for (int t = tbeg; t < tend; ++t) {
    u32x2 X[4];
    LOADX(X, t - 16 * k);
    STEPF(X);
  }
#undef STEPF
#undef MULPK
#undef LOADX
#undef SWAPQ

  // ---- transpose via LDS, pack bf16, store row-major ----
#pragma unroll
  for (int r = 0; r < 4; ++r) {
    trs[(4 * q + r) * 68      + 16 * wid + c] = g0[r];
    trs[(16 + 4 * q + r) * 68 + 16 * wid + c] = g1[r];
    trs[(32 + 4 * q + r) * 68 + 16 * wid + c] = g2[r];
    trs[(48 + 4 * q + r) * 68 + 16 * wid + c] = g3[r];
  }
  __syncthreads();
  {
    int row = tid >> 2, qt = tid & 3;
    const float* src = trs + row * 68 + qt * 16;
    u32 wp[8];
#pragma unroll
    for (int m = 0; m < 8; ++m) wp[m] = cvt_pk_bf16(src[2 * m], src[2 * m + 1]);
    u32x4* dst = (u32x4*)(Gout + (((size_t)(b * 16 + k) * 64 + row) * 64 + qt * 16));
    dst[0] = *(u32x4*)&wp[0];
    dst[1] = *(u32x4*)&wp[4];
  }
}

// ---------------------------------------------------------------------------
// Kernel 3: per-batch alpha scan through 16 chunk matrices (bf16, no scales
// — R3/R4-proven); gold from Gpart; atomicAdd into out (64 atomics).
// ---------------------------------------------------------------------------
__global__ __launch_bounds__(64, 1) void chain_apply(
    const unsigned short* __restrict__ xbuf, const float* __restrict__ trans,
    const unsigned short* __restrict__ Gout, const float* __restrict__ Gpart,
    const int* __restrict__ seq_lens, float* __restrict__ out) {
  __shared__ __align__(16) float elds[64];
  const int b = blockIdx.x;
  const int j = threadIdx.x;
  const int L = seq_lens[b];

  float gp = (j < 16) ? Gpart[b * 16 + j] : 0.f;
  gp += __shfl_xor(gp, 1, 64);
  gp += __shfl_xor(gp, 2, 64);
  gp += __shfl_xor(gp, 4, 64);
  gp += __shfl_xor(gp, 8, 64);

  float A    = __expf(trans[j]);                                         // trans[BOS][j]
  float logZ = __logf(__uint_as_float((u32)xbuf[(size_t)b * NT] << 16)); // emit[0,b,BOS]

  const unsigned short* gbase = Gout + (size_t)b * 16 * 4096 + (size_t)j * 64;
  u32x4 gc[8], gn[8];
#pragma unroll
  for (int m = 0; m < 8; ++m) gc[m] = *((const u32x4*)gbase + m);

  const float C6 = 6.f * 0.6931471805599453f;

  for (int k = 0; k < 16; ++k) {
    if (k < 15) {
      const u32x4* gb2 = (const u32x4*)(gbase + (size_t)(k + 1) * 4096);
#pragma unroll
      for (int m = 0; m < 8; ++m) gn[m] = gb2[m];
    }
    int tb = 16 * k; if (tb < 1) tb = 1;
    int te = 16 * k + 16; if (te > L) te = L;
    int n = te - tb;
    if (n > 0) {
      elds[j] = A;                    // same-wave DS ordering (R1-proven)
      float s0 = 0.f, s1 = 0.f, s2 = 0.f, s3 = 0.f;
#pragma unroll
      for (int m = 0; m < 8; ++m) {
        f32x4 av0 = *(const f32x4*)(elds + 8 * m);
        f32x4 av1 = *(const f32x4*)(elds + 8 * m + 4);
        u32x4 w = gc[m];
        s0 = fmaf(av0.x, __uint_as_float(w.x << 16),         s0);
        s1 = fmaf(av0.y, __uint_as_float(w.x & 0xFFFF0000u), s1);
        s2 = fmaf(av0.z, __uint_as_float(w.y << 16),         s2);
        s3 = fmaf(av0.w, __uint_as_float(w.y & 0xFFFF0000u), s3);
        s0 = fmaf(av1.x, __uint_as_float(w.z << 16),         s0);
        s1 = fmaf(av1.y, __uint_as_float(w.z & 0xFFFF0000u), s1);
        s2 = fmaf(av1.z, __uint_as_float(w.w << 16),         s2);
        s3 = fmaf(av1.w, __uint_as_float(w.w & 0xFFFF0000u), s3);
      }
      A = (s0 + s1) + (s2 + s3);
      logZ += C6 * (float)n;
      u32 bb = __builtin_amdgcn_readfirstlane(__float_as_uint(A));
      int ex = (int)((bb >> 23) & 255u) - 127;
      A *= __uint_as_float((u32)(127 - ex) << 23);
      logZ += (float)ex * 0.6931471805599453f;
    }
    if (k < 15) {
#pragma unroll
      for (int m = 0; m < 8; ++m) gc[m] = gn[m];
    }
  }

  float res = logZ + __logf(A);
  res = __shfl(res, 1, 64);           // EOS = 1
  if (j == 0) atomicAdd(out, res - gp);
}

extern "C" void kernel_launch(void* const* d_in, const int* in_sizes, int n_in,
                              void* d_out, int out_size, void* d_ws, size_t ws_size,
                              hipStream_t stream) {
  const float* F     = (const float*)d_in[0];   // features (S,B,D) f32
  const int*   tags  = (const int*)  d_in[1];   // (S,B) i32
  const int*   seq   = (const int*)  d_in[2];   // (B,) i32
  const float* W     = (const float*)d_in[3];   // (T,D) f32
  const float* bias  = (const float*)d_in[4];   // (T,) f32
  const float* trans = (const float*)d_in[5];   // (T,T) f32
  float* out = (float*)d_out;

  char* ws = (char*)d_ws;
  // xbuf  : 272 rows x 4096 bf16                     @ 0         (2,228,224 B)
  // Wb3   : 128 KiB                                  @ 2228224
  // Ebuf  : 16 KiB (bf16 hi/lo E table)              @ 2359296
  // Gout  : 64b x 16k x 64 x 64 bf16 = 8 MiB         @ 2375680
  // Gpart : 64 x 16 f32 = 4 KiB                      @ 10764288  (ends 10,768,384)
  unsigned short* xbuf  = (unsigned short*)ws;
  unsigned short* Wb3   = (unsigned short*)(ws + 2228224);
  u32*            Ebuf  = (u32*)(ws + 2359296);
  unsigned short* Gout  = (unsigned short*)(ws + 2375680);
  float*          Gpart = (float*)(ws + 10764288);

  prep       <<<257,  256, 0, stream>>>(W, trans, Wb3, Ebuf, out);
  emit_gemm  <<<1024, 256, 0, stream>>>(F, Wb3, bias, xbuf);
  chunk_prod <<<1024, 256, 0, stream>>>(xbuf, trans, Ebuf, tags, seq, Gout, Gpart);
  chain_apply<<<64,    64, 0, stream>>>(xbuf, trans, Gout, Gpart, seq, out);
}